// Round 3
// baseline (12370.557 us; speedup 1.0000x reference)
//
#include <hip/hip_runtime.h>
#include <math.h>

#define N_NODESC 50000
#define N_EDGESC 200000
#define N_GRAPHSC 256
#define D_INC 100
#define HD 384
#define STEPSC 4
#define BN_EPS 1e-5f

// fixed-point scale for deterministic edge aggregation (int32 atomics are
// order-independent -> bit-exact across graph replays). |agg| < 512 guaranteed
// (realistic max ~64), quantization 2^-23 per edge ~ fp32 ulp.
#define FPSCALE 4194304.0f        // 2^22
#define FPINV   (1.0f / 4194304.0f)

#define STATS_ROWS 512
#define STATS_BLOCKS 98           // ceil(50000/512)

static __device__ __forceinline__ float sigmoidf_(float x) { return 1.0f / (1.0f + expf(-x)); }

// ---------------- GEMM: C[M,N] = A[M,K] @ B[K,N] (+bias) ----------------
__global__ __launch_bounds__(256) void gemm64(const float* __restrict__ A,
                                              const float* __restrict__ B,
                                              const float* __restrict__ bias,
                                              float* __restrict__ C,
                                              int M, int K, int N) {
    __shared__ float As[16][68];
    __shared__ float Bs[16][68];
    const int tid = threadIdx.x;
    const int tx = tid & 15, ty = tid >> 4;
    const int m0 = blockIdx.y << 6, n0 = blockIdx.x << 6;
    const int ar = tid >> 2, ac4 = tid & 3;
    const int br = tid >> 4, bc4 = tid & 15;
    float acc[4][4] = {};
    for (int k0 = 0; k0 < K; k0 += 16) {
        float4 av = make_float4(0.f, 0.f, 0.f, 0.f);
        const int arow = m0 + ar, ak = k0 + (ac4 << 2);
        if (arow < M && ak < K) av = *(const float4*)(A + (size_t)arow * K + ak);
        As[(ac4 << 2) + 0][ar] = av.x;
        As[(ac4 << 2) + 1][ar] = av.y;
        As[(ac4 << 2) + 2][ar] = av.z;
        As[(ac4 << 2) + 3][ar] = av.w;
        float4 bv = make_float4(0.f, 0.f, 0.f, 0.f);
        const int bk = k0 + br;
        if (bk < K) bv = *(const float4*)(B + (size_t)bk * N + n0 + (bc4 << 2));
        *(float4*)&Bs[br][bc4 << 2] = bv;
        __syncthreads();
#pragma unroll
        for (int kk = 0; kk < 16; ++kk) {
            const float4 a = *(const float4*)&As[kk][ty << 2];
            const float4 b = *(const float4*)&Bs[kk][tx << 2];
            const float aarr[4] = {a.x, a.y, a.z, a.w};
            const float barr[4] = {b.x, b.y, b.z, b.w};
#pragma unroll
            for (int i = 0; i < 4; ++i)
#pragma unroll
                for (int j = 0; j < 4; ++j) acc[i][j] = fmaf(aarr[i], barr[j], acc[i][j]);
        }
        __syncthreads();
    }
#pragma unroll
    for (int i = 0; i < 4; ++i) {
        const int row = m0 + (ty << 2) + i;
        if (row >= M) continue;
        const int col0 = n0 + (tx << 2);
        float4 out;
        out.x = acc[i][0]; out.y = acc[i][1]; out.z = acc[i][2]; out.w = acc[i][3];
        if (bias) {
            out.x += bias[col0 + 0]; out.y += bias[col0 + 1];
            out.z += bias[col0 + 2]; out.w += bias[col0 + 3];
        }
        *(float4*)(C + (size_t)row * HD + 0) , (void)0;  // no-op guard against miscompile
        *(float4*)(C + (size_t)row * N + col0) = out;
    }
}

// ---------------- Fused GRU (agg is int32 fixed-point) ----------------
__global__ __launch_bounds__(256) void gru_fused(const int* __restrict__ aggi,
                                                 const float* __restrict__ hin,
                                                 const float* __restrict__ wih,
                                                 const float* __restrict__ whh,
                                                 const float* __restrict__ bih,
                                                 const float* __restrict__ bhh,
                                                 float* __restrict__ hout) {
    __shared__ float Aa[16][68];
    __shared__ float Ahs[16][68];
    __shared__ float Bs[6][16][68];
    const int tid = threadIdx.x;
    const int tx = tid & 15, ty = tid >> 4;
    const int m0 = blockIdx.y << 6, j0 = blockIdx.x << 6;
    const int ar = tid >> 2, ac4 = tid & 3;
    float ai[3][4][4] = {};
    float ah[3][4][4] = {};
    for (int k0 = 0; k0 < HD; k0 += 16) {
        const int arow = m0 + ar;
        float4 av = make_float4(0.f, 0.f, 0.f, 0.f);
        float4 hv = make_float4(0.f, 0.f, 0.f, 0.f);
        if (arow < N_NODESC) {
            const int4 q = *(const int4*)(aggi + (size_t)arow * HD + k0 + (ac4 << 2));
            av = make_float4(q.x * FPINV, q.y * FPINV, q.z * FPINV, q.w * FPINV);
            hv = *(const float4*)(hin + (size_t)arow * HD + k0 + (ac4 << 2));
        }
        Aa[(ac4 << 2) + 0][ar] = av.x; Aa[(ac4 << 2) + 1][ar] = av.y;
        Aa[(ac4 << 2) + 2][ar] = av.z; Aa[(ac4 << 2) + 3][ar] = av.w;
        Ahs[(ac4 << 2) + 0][ar] = hv.x; Ahs[(ac4 << 2) + 1][ar] = hv.y;
        Ahs[(ac4 << 2) + 2][ar] = hv.z; Ahs[(ac4 << 2) + 3][ar] = hv.w;
#pragma unroll
        for (int t6 = 0; t6 < 6; ++t6) {
            const float* W = (t6 < 3) ? wih : whh;
            const int gate = (t6 < 3) ? t6 : t6 - 3;
            const float4 wv = *(const float4*)(W + (size_t)(gate * HD + j0 + ar) * HD + k0 + (ac4 << 2));
            Bs[t6][(ac4 << 2) + 0][ar] = wv.x; Bs[t6][(ac4 << 2) + 1][ar] = wv.y;
            Bs[t6][(ac4 << 2) + 2][ar] = wv.z; Bs[t6][(ac4 << 2) + 3][ar] = wv.w;
        }
        __syncthreads();
#pragma unroll
        for (int kk = 0; kk < 16; ++kk) {
            const float4 a4 = *(const float4*)&Aa[kk][ty << 2];
            const float4 h4 = *(const float4*)&Ahs[kk][ty << 2];
            const float aarr[4] = {a4.x, a4.y, a4.z, a4.w};
            const float harr[4] = {h4.x, h4.y, h4.z, h4.w};
#pragma unroll
            for (int g = 0; g < 3; ++g) {
                const float4 bi4 = *(const float4*)&Bs[g][kk][tx << 2];
                const float4 bh4 = *(const float4*)&Bs[g + 3][kk][tx << 2];
                const float bi[4] = {bi4.x, bi4.y, bi4.z, bi4.w};
                const float bh[4] = {bh4.x, bh4.y, bh4.z, bh4.w};
#pragma unroll
                for (int i = 0; i < 4; ++i)
#pragma unroll
                    for (int j = 0; j < 4; ++j) {
                        ai[g][i][j] = fmaf(aarr[i], bi[j], ai[g][i][j]);
                        ah[g][i][j] = fmaf(harr[i], bh[j], ah[g][i][j]);
                    }
            }
        }
        __syncthreads();
    }
#pragma unroll
    for (int i = 0; i < 4; ++i) {
        const int row = m0 + (ty << 2) + i;
        if (row >= N_NODESC) continue;
        const int col0 = j0 + (tx << 2);
        const float4 hold4 = *(const float4*)(hin + (size_t)row * HD + col0);
        const float holda[4] = {hold4.x, hold4.y, hold4.z, hold4.w};
        float res[4];
#pragma unroll
        for (int j = 0; j < 4; ++j) {
            const int col = col0 + j;
            const float ir = ai[0][i][j] + bih[col];
            const float iz = ai[1][i][j] + bih[HD + col];
            const float in_ = ai[2][i][j] + bih[2 * HD + col];
            const float hr = ah[0][i][j] + bhh[col];
            const float hz = ah[1][i][j] + bhh[HD + col];
            const float hn = ah[2][i][j] + bhh[2 * HD + col];
            const float r = sigmoidf_(ir + hr);
            const float z = sigmoidf_(iz + hz);
            const float n = tanhf(in_ + r * hn);
            res[j] = (1.f - z) * n + z * holda[j];
        }
        float4 o; o.x = res[0]; o.y = res[1]; o.z = res[2]; o.w = res[3];
        *(float4*)(hout + (size_t)row * HD + col0) = o;
    }
}

// ---------------- edge scatter: deterministic int32 fixed-point ----------------
__global__ __launch_bounds__(256) void scatter_add(const float* __restrict__ m,
                                                   const int* __restrict__ src,
                                                   const int* __restrict__ dst,
                                                   int* __restrict__ aggi) {
    const int gid = blockIdx.x * 256 + threadIdx.x;  // E*96 threads exactly
    const int e = gid / 96;
    const int c = gid % 96;
    if (e >= N_EDGESC) return;
    const int s = src[e], d = dst[e];
    const float4 v = *(const float4*)(m + (size_t)s * HD + (c << 2));
    int* o = aggi + (size_t)d * HD + (c << 2);
    atomicAdd(o + 0, __float2int_rn(v.x * FPSCALE));
    atomicAdd(o + 1, __float2int_rn(v.y * FPSCALE));
    atomicAdd(o + 2, __float2int_rn(v.z * FPSCALE));
    atomicAdd(o + 3, __float2int_rn(v.w * FPSCALE));
}

// ---------------- BN stats: deterministic two-stage ----------------
__global__ __launch_bounds__(384) void col_stats_partial(const float* __restrict__ X, int M,
                                                         float* __restrict__ pS,
                                                         float* __restrict__ pQ) {
    const int f = threadIdx.x;
    const int b = blockIdx.x;
    const int r0 = b * STATS_ROWS;
    const int r1 = min(r0 + STATS_ROWS, M);
    float s = 0.f, q = 0.f;
    for (int r = r0; r < r1; ++r) {
        const float v = X[(size_t)r * HD + f];
        s += v;
        q += v * v;
    }
    pS[b * HD + f] = s;
    pQ[b * HD + f] = q;
}

__global__ void bn_stats_final(const float* __restrict__ pS, const float* __restrict__ pQ,
                               const float* __restrict__ g, const float* __restrict__ b,
                               float* __restrict__ scale, float* __restrict__ shift, float invM) {
    const int f = threadIdx.x;
    float s = 0.f, q = 0.f;
    for (int blk = 0; blk < STATS_BLOCKS; ++blk) {  // fixed order -> deterministic
        s += pS[blk * HD + f];
        q += pQ[blk * HD + f];
    }
    const float mean = s * invM;
    const float var = q * invM - mean * mean;
    const float sc = g[f] * rsqrtf(var + BN_EPS);
    scale[f] = sc;
    shift[f] = b[f] - mean * sc;
}

// h = relu(X*scale + shift)  (X may alias h; no restrict on those)
__global__ __launch_bounds__(256) void bn_relu_apply(const float* X,
                                                     const float* __restrict__ scale,
                                                     const float* __restrict__ shift,
                                                     float* h) {
    const size_t i4 = (size_t)blockIdx.x * 256 + threadIdx.x;
    if (i4 >= (size_t)N_NODESC * HD / 4) return;
    const int f = (int)((i4 * 4) % HD);
    const float4 v = ((const float4*)X)[i4];
    float4 r;
    r.x = fmaxf(fmaf(v.x, scale[f + 0], shift[f + 0]), 0.f);
    r.y = fmaxf(fmaf(v.y, scale[f + 1], shift[f + 1]), 0.f);
    r.z = fmaxf(fmaf(v.z, scale[f + 2], shift[f + 2]), 0.f);
    r.w = fmaxf(fmaf(v.w, scale[f + 3], shift[f + 3]), 0.f);
    ((float4*)h)[i4] = r;
}

// h = relu(h*scale + shift + skip)  (in place on h)
__global__ __launch_bounds__(256) void bn_skip_relu(const float* __restrict__ scale,
                                                    const float* __restrict__ shift,
                                                    const float* __restrict__ skip,
                                                    float* h) {
    const size_t i4 = (size_t)blockIdx.x * 256 + threadIdx.x;
    if (i4 >= (size_t)N_NODESC * HD / 4) return;
    const int f = (int)((i4 * 4) % HD);
    const float4 v = ((const float4*)h)[i4];
    const float4 s = ((const float4*)skip)[i4];
    float4 r;
    r.x = fmaxf(fmaf(v.x, scale[f + 0], shift[f + 0]) + s.x, 0.f);
    r.y = fmaxf(fmaf(v.y, scale[f + 1], shift[f + 1]) + s.y, 0.f);
    r.z = fmaxf(fmaf(v.z, scale[f + 2], shift[f + 2]) + s.z, 0.f);
    r.w = fmaxf(fmaf(v.w, scale[f + 3], shift[f + 3]) + s.w, 0.f);
    ((float4*)h)[i4] = r;
}

// ---------------- attention logits: one wave per node ----------------
__global__ __launch_bounds__(64) void att_logits(const float* __restrict__ h2,
                                                 const float* __restrict__ att_w,
                                                 const float* __restrict__ att_b,
                                                 float* __restrict__ logits) {
    const int n = blockIdx.x;
    const int l = threadIdx.x;
    float acc = 0.f;
#pragma unroll
    for (int k = 0; k < HD; k += 64) acc += h2[(size_t)n * HD + k + l] * att_w[k + l];
#pragma unroll
    for (int o = 32; o > 0; o >>= 1) acc += __shfl_down(acc, o);
    if (l == 0) logits[n] = acc + att_b[0];
}

__global__ void count_graphs(const int* __restrict__ batch, int* __restrict__ counts) {
    const int n = blockIdx.x * 256 + threadIdx.x;
    if (n < N_NODESC) atomicAdd(&counts[batch[n]], 1);  // int atomics: deterministic
}

__global__ void scan_offsets(const int* __restrict__ counts, int* __restrict__ offs) {
    __shared__ int tmp[N_GRAPHSC];
    const int t = threadIdx.x;
    tmp[t] = counts[t];
    __syncthreads();
    for (int o = 1; o < N_GRAPHSC; o <<= 1) {
        int v = (t >= o) ? tmp[t - o] : 0;
        __syncthreads();
        tmp[t] += v;
        __syncthreads();
    }
    offs[t] = tmp[t] - counts[t];
}

// ---------------- per-graph softmax-attention pooling ----------------
__global__ __launch_bounds__(384) void pool_graphs(const float* __restrict__ h2,
                                                   const float* __restrict__ logits,
                                                   const int* __restrict__ offs,
                                                   const int* __restrict__ counts,
                                                   float* __restrict__ pooled) {
    const int g = blockIdx.x;
    const int t = threadIdx.x;
    const int s = offs[g], c = counts[g], e = s + c;
    __shared__ float red[384];
    float mx = -1e30f;
    for (int n = s + t; n < e; n += 384) mx = fmaxf(mx, logits[n]);
    red[t] = mx;
    __syncthreads();
    if (t < 128) red[t] = fmaxf(red[t], fmaxf(red[t + 128], red[t + 256]));
    __syncthreads();
    for (int w = 64; w > 0; w >>= 1) {
        if (t < w) red[t] = fmaxf(red[t], red[t + w]);
        __syncthreads();
    }
    mx = red[0];
    __syncthreads();
    float sm = 0.f;
    for (int n = s + t; n < e; n += 384) sm += expf(logits[n] - mx);
    red[t] = sm;
    __syncthreads();
    if (t < 128) red[t] += red[t + 128] + red[t + 256];
    __syncthreads();
    for (int w = 64; w > 0; w >>= 1) {
        if (t < w) red[t] += red[t + w];
        __syncthreads();
    }
    const float denom = red[0];
    const float inv = (c > 0) ? 1.0f / denom : 0.0f;
    float acc = 0.f;
    for (int n = s; n < e; ++n) acc += expf(logits[n] - mx) * h2[(size_t)n * HD + t];
    pooled[(size_t)g * HD + t] = acc * inv;
}

// ---------------- small FC + BN ----------------
__global__ void fc_small(const float* __restrict__ X, const float* __restrict__ W,
                         const float* __restrict__ bias, float* __restrict__ Y,
                         int K, int N) {
    const int m = blockIdx.x;
    const int n = threadIdx.x;
    if (n >= N) return;
    float acc = bias[n];
    for (int k = 0; k < K; ++k) acc += X[m * K + k] * W[k * N + n];
    Y[m * N + n] = acc;
}

__global__ void bn_small_relu(float* X, int M, int N,
                              const float* __restrict__ g, const float* __restrict__ b) {
    const int f = threadIdx.x;
    if (f >= N) return;
    float s = 0.f, q = 0.f;
    for (int r = 0; r < M; ++r) {
        const float v = X[r * N + f];
        s += v;
        q += v * v;
    }
    const float mean = s / M;
    const float var = q / M - mean * mean;
    const float sc = g[f] * rsqrtf(var + BN_EPS);
    const float sh = b[f] - mean * sc;
    for (int r = 0; r < M; ++r) X[r * N + f] = fmaxf(X[r * N + f] * sc + sh, 0.f);
}

extern "C" void kernel_launch(void* const* d_in, const int* in_sizes, int n_in,
                              void* d_out, int out_size, void* d_ws, size_t ws_size,
                              hipStream_t stream) {
    const float* x       = (const float*)d_in[0];
    const int*   eidx    = (const int*)d_in[1];
    const int*   batch   = (const int*)d_in[2];
    const float* w_in    = (const float*)d_in[3];
    const float* b_in    = (const float*)d_in[4];
    const float* bn1_g   = (const float*)d_in[5];
    const float* bn1_b   = (const float*)d_in[6];
    const float* ggc_w   = (const float*)d_in[7];
    const float* gru_wih = (const float*)d_in[8];
    const float* gru_whh = (const float*)d_in[9];
    const float* gru_bih = (const float*)d_in[10];
    const float* gru_bhh = (const float*)d_in[11];
    const float* bn2_g   = (const float*)d_in[12];
    const float* bn2_b   = (const float*)d_in[13];
    const float* att_w   = (const float*)d_in[14];
    const float* att_b   = (const float*)d_in[15];
    const float* fc1_w   = (const float*)d_in[16];
    const float* fc1_b   = (const float*)d_in[17];
    const float* bn3_g   = (const float*)d_in[18];
    const float* bn3_b   = (const float*)d_in[19];
    const float* fc2_w   = (const float*)d_in[20];
    const float* fc2_b   = (const float*)d_in[21];
    const float* bn4_g   = (const float*)d_in[22];
    const float* bn4_b   = (const float*)d_in[23];
    const float* fc3_w   = (const float*)d_in[24];
    const float* fc3_b   = (const float*)d_in[25];

    const int* src = eidx;
    const int* dst = eidx + N_EDGESC;

    // ---- workspace layout: 3 big NH buffers + ~1.5 MB small (~232 MB) ----
    const size_t NH = (size_t)N_NODESC * HD;
    float* buf0   = (float*)d_ws;
    float* buf1   = buf0 + NH;
    int*   aggi   = (int*)(buf1 + NH);
    float* logits = (float*)(aggi + NH);   // 50000
    float* pS     = logits + N_NODESC;     // 98*384
    float* pQ     = pS + STATS_BLOCKS * HD;
    float* scale  = pQ + STATS_BLOCKS * HD;  // bn2 affine
    float* shift  = scale + HD;
    float* scale1 = shift + HD;              // bn1 affine (for skip recompute)
    float* shift1 = scale1 + HD;
    float* pooled = shift1 + HD;           // 256*384
    float* y1     = pooled + N_GRAPHSC * HD;
    float* y2     = y1 + N_GRAPHSC * HD;   // 256*192
    int*   counts = (int*)(y2 + N_GRAPHSC * (HD / 2));
    int*   offs   = counts + N_GRAPHSC;

    const int mtiles = (N_NODESC + 63) / 64;
    const dim3 gemm_grid(HD / 64, mtiles);
    const int ew_blocks = (int)(NH / 4 / 256);  // 18750 exact

    // 1) input layer + bn1 + relu -> h (buf0)
    gemm64<<<gemm_grid, 256, 0, stream>>>(x, w_in, b_in, buf1, N_NODESC, D_INC, HD);
    col_stats_partial<<<STATS_BLOCKS, 384, 0, stream>>>(buf1, N_NODESC, pS, pQ);
    bn_stats_final<<<1, 384, 0, stream>>>(pS, pQ, bn1_g, bn1_b, scale1, shift1, 1.0f / N_NODESC);
    bn_relu_apply<<<ew_blocks, 256, 0, stream>>>(buf1, scale1, shift1, buf0);

    // 2) GatedGraphConv steps
    float* pH = buf0;
    float* pM = buf1;
    for (int s7 = 0; s7 < STEPSC; ++s7) {
        gemm64<<<gemm_grid, 256, 0, stream>>>(pH, ggc_w + (size_t)s7 * HD * HD, nullptr, pM,
                                              N_NODESC, HD, HD);
        hipMemsetAsync(aggi, 0, NH * sizeof(int), stream);
        scatter_add<<<(N_EDGESC * 96) / 256, 256, 0, stream>>>(pM, src, dst, aggi);
        gru_fused<<<gemm_grid, 256, 0, stream>>>(aggi, pH, gru_wih, gru_whh, gru_bih, gru_bhh, pM);
        float* t = pH; pH = pM; pM = t;
    }

    // 3) bn2 stats on pH; recompute skip into pM; fused bn2+skip+relu on pH
    col_stats_partial<<<STATS_BLOCKS, 384, 0, stream>>>(pH, N_NODESC, pS, pQ);
    bn_stats_final<<<1, 384, 0, stream>>>(pS, pQ, bn2_g, bn2_b, scale, shift, 1.0f / N_NODESC);
    gemm64<<<gemm_grid, 256, 0, stream>>>(x, w_in, b_in, pM, N_NODESC, D_INC, HD);
    bn_relu_apply<<<ew_blocks, 256, 0, stream>>>(pM, scale1, shift1, pM);
    bn_skip_relu<<<ew_blocks, 256, 0, stream>>>(scale, shift, pM, pH);

    // 4) attention pooling
    att_logits<<<N_NODESC, 64, 0, stream>>>(pH, att_w, att_b, logits);
    hipMemsetAsync(counts, 0, N_GRAPHSC * sizeof(int), stream);
    count_graphs<<<(N_NODESC + 255) / 256, 256, 0, stream>>>(batch, counts);
    scan_offsets<<<1, N_GRAPHSC, 0, stream>>>(counts, offs);
    pool_graphs<<<N_GRAPHSC, 384, 0, stream>>>(pH, logits, offs, counts, pooled);

    // 5) MLP head
    fc_small<<<N_GRAPHSC, 384, 0, stream>>>(pooled, fc1_w, fc1_b, y1, HD, HD);
    bn_small_relu<<<1, 384, 0, stream>>>(y1, N_GRAPHSC, HD, bn3_g, bn3_b);
    fc_small<<<N_GRAPHSC, 192, 0, stream>>>(y1, fc2_w, fc2_b, y2, HD, HD / 2);
    bn_small_relu<<<1, 192, 0, stream>>>(y2, N_GRAPHSC, HD / 2, bn4_g, bn4_b);
    fc_small<<<N_GRAPHSC, 64, 0, stream>>>(y2, fc3_w, fc3_b, (float*)d_out, HD / 2, 2);
}

// Round 4
// 9092.201 us; speedup vs baseline: 1.3606x; 1.3606x over previous
//
#include <hip/hip_runtime.h>
#include <math.h>

#define N_NODESC 50000
#define N_EDGESC 200000
#define N_GRAPHSC 256
#define D_INC 100
#define HD 384
#define STEPSC 4
#define BN_EPS 1e-5f

// deterministic edge aggregation: int32 fixed-point atomics (order-independent)
#define FPSCALE 4194304.0f        // 2^22
#define FPINV   (1.0f / 4194304.0f)

#define STATS_ROWS 512
#define STATS_BLOCKS 98           // ceil(50000/512)

typedef _Float16 h8v __attribute__((ext_vector_type(8)));
typedef _Float16 h4v __attribute__((ext_vector_type(4)));
typedef float f4v __attribute__((ext_vector_type(4)));

static __device__ __forceinline__ float sigmoidf_(float x) { return 1.0f / (1.0f + expf(-x)); }

// ================= fp32 GEMM (kept for K=100 input layer) =================
__global__ __launch_bounds__(256) void gemm64(const float* __restrict__ A,
                                              const float* __restrict__ B,
                                              const float* __restrict__ bias,
                                              float* __restrict__ C,
                                              int M, int K, int N) {
    __shared__ float As[16][68];
    __shared__ float Bs[16][68];
    const int tid = threadIdx.x;
    const int tx = tid & 15, ty = tid >> 4;
    const int m0 = blockIdx.y << 6, n0 = blockIdx.x << 6;
    const int ar = tid >> 2, ac4 = tid & 3;
    const int br = tid >> 4, bc4 = tid & 15;
    float acc[4][4] = {};
    for (int k0 = 0; k0 < K; k0 += 16) {
        float4 av = make_float4(0.f, 0.f, 0.f, 0.f);
        const int arow = m0 + ar, ak = k0 + (ac4 << 2);
        if (arow < M && ak < K) av = *(const float4*)(A + (size_t)arow * K + ak);
        As[(ac4 << 2) + 0][ar] = av.x;
        As[(ac4 << 2) + 1][ar] = av.y;
        As[(ac4 << 2) + 2][ar] = av.z;
        As[(ac4 << 2) + 3][ar] = av.w;
        float4 bv = make_float4(0.f, 0.f, 0.f, 0.f);
        const int bk = k0 + br;
        if (bk < K) bv = *(const float4*)(B + (size_t)bk * N + n0 + (bc4 << 2));
        *(float4*)&Bs[br][bc4 << 2] = bv;
        __syncthreads();
#pragma unroll
        for (int kk = 0; kk < 16; ++kk) {
            const float4 a = *(const float4*)&As[kk][ty << 2];
            const float4 b = *(const float4*)&Bs[kk][tx << 2];
            const float aarr[4] = {a.x, a.y, a.z, a.w};
            const float barr[4] = {b.x, b.y, b.z, b.w};
#pragma unroll
            for (int i = 0; i < 4; ++i)
#pragma unroll
                for (int j = 0; j < 4; ++j) acc[i][j] = fmaf(aarr[i], barr[j], acc[i][j]);
        }
        __syncthreads();
    }
#pragma unroll
    for (int i = 0; i < 4; ++i) {
        const int row = m0 + (ty << 2) + i;
        if (row >= M) continue;
        const int col0 = n0 + (tx << 2);
        float4 out;
        out.x = acc[i][0]; out.y = acc[i][1]; out.z = acc[i][2]; out.w = acc[i][3];
        if (bias) {
            out.x += bias[col0 + 0]; out.y += bias[col0 + 1];
            out.z += bias[col0 + 2]; out.w += bias[col0 + 3];
        }
        *(float4*)(C + (size_t)row * N + col0) = out;
    }
}

// ================= weight prep: fp16x2 splits =================
// straight split: [out][k] row-major fp32 -> hi/lo halves (same layout)
__global__ __launch_bounds__(256) void split_w(const float* __restrict__ src,
                                               _Float16* __restrict__ hi,
                                               _Float16* __restrict__ lo, int n4) {
    const int i = blockIdx.x * 256 + threadIdx.x;
    if (i >= n4) return;
    const float4 v = ((const float4*)src)[i];
    h4v a, b;
    a[0] = (_Float16)v.x; b[0] = (_Float16)(v.x - (float)a[0]);
    a[1] = (_Float16)v.y; b[1] = (_Float16)(v.y - (float)a[1]);
    a[2] = (_Float16)v.z; b[2] = (_Float16)(v.z - (float)a[2]);
    a[3] = (_Float16)v.w; b[3] = (_Float16)(v.w - (float)a[3]);
    *(h4v*)(hi + (size_t)i * 4) = a;
    *(h4v*)(lo + (size_t)i * 4) = b;
}

// ggc_w[s][k][n] -> transposed split T[s][n][k] (out-major, k contiguous)
__global__ __launch_bounds__(256) void tsplit_ggc(const float* __restrict__ w,
                                                  _Float16* __restrict__ hi,
                                                  _Float16* __restrict__ lo) {
    const int i = blockIdx.x * 256 + threadIdx.x;  // over 4*384*384
    if (i >= STEPSC * HD * HD) return;
    const int s = i / (HD * HD), r = i % (HD * HD), n = r / HD, k = r % HD;
    const float v = w[(size_t)s * HD * HD + (size_t)k * HD + n];
    const _Float16 h = (_Float16)v;
    hi[i] = h;
    lo[i] = (_Float16)(v - (float)h);
}

// ================= MFMA GEMM: m = h @ ggc_w[s]  (fp16x2 split) =================
// block 256 thr = 4 waves (2x2), wave tile 32x32, 16x16x32_f16, no LDS.
__global__ __launch_bounds__(256) void ggc_mfma(const _Float16* __restrict__ hH,
                                                const _Float16* __restrict__ hL,
                                                const _Float16* __restrict__ wtH,
                                                const _Float16* __restrict__ wtL,
                                                _Float16* __restrict__ mH,
                                                _Float16* __restrict__ mL) {
    const int tid = threadIdx.x;
    const int wid = tid >> 6, lane = tid & 63;
    const int lr = lane & 15, lk = lane >> 4;
    const int wr = wid >> 1, wc = wid & 1;
    const int m0 = blockIdx.y << 6;
    const int j0 = blockIdx.x << 6;
    int arow[2];
    arow[0] = min(m0 + wr * 32 + lr, N_NODESC - 1);
    arow[1] = min(m0 + wr * 32 + 16 + lr, N_NODESC - 1);
    const int jb = j0 + wc * 32 + lr;
    const int kb = lk * 8;
    f4v acc[2][2];
    const f4v z4 = {0.f, 0.f, 0.f, 0.f};
#pragma unroll
    for (int a = 0; a < 2; ++a)
#pragma unroll
        for (int b = 0; b < 2; ++b) acc[a][b] = z4;
    for (int k0 = 0; k0 < HD; k0 += 32) {
        h8v Ah[2], Al[2], Bh[2], Bl[2];
#pragma unroll
        for (int sm = 0; sm < 2; ++sm) {
            const size_t off = (size_t)arow[sm] * HD + k0 + kb;
            Ah[sm] = *(const h8v*)(hH + off);
            Al[sm] = *(const h8v*)(hL + off);
        }
#pragma unroll
        for (int sn = 0; sn < 2; ++sn) {
            const size_t woff = (size_t)(jb + sn * 16) * HD + k0 + kb;
            Bh[sn] = *(const h8v*)(wtH + woff);
            Bl[sn] = *(const h8v*)(wtL + woff);
        }
#pragma unroll
        for (int sm = 0; sm < 2; ++sm)
#pragma unroll
            for (int sn = 0; sn < 2; ++sn) {
                acc[sm][sn] = __builtin_amdgcn_mfma_f32_16x16x32_f16(Ah[sm], Bh[sn], acc[sm][sn], 0, 0, 0);
                acc[sm][sn] = __builtin_amdgcn_mfma_f32_16x16x32_f16(Ah[sm], Bl[sn], acc[sm][sn], 0, 0, 0);
                acc[sm][sn] = __builtin_amdgcn_mfma_f32_16x16x32_f16(Al[sm], Bh[sn], acc[sm][sn], 0, 0, 0);
            }
    }
#pragma unroll
    for (int sm = 0; sm < 2; ++sm)
#pragma unroll
        for (int sn = 0; sn < 2; ++sn) {
            const int col = j0 + wc * 32 + sn * 16 + lr;
#pragma unroll
            for (int j = 0; j < 4; ++j) {
                const int row = m0 + wr * 32 + sm * 16 + lk * 4 + j;
                if (row < N_NODESC) {
                    const size_t off = (size_t)row * HD + col;
                    const float v = acc[sm][sn][j];
                    const _Float16 h = (_Float16)v;
                    mH[off] = h;
                    mL[off] = (_Float16)(v - (float)h);
                }
            }
        }
}

// ================= MFMA fused GRU: 6 gate GEMMs + update =================
__global__ __launch_bounds__(256) void gru_mfma(const _Float16* __restrict__ aH,
                                                const _Float16* __restrict__ aL,
                                                const _Float16* __restrict__ hH,
                                                const _Float16* __restrict__ hL,
                                                const _Float16* __restrict__ wihH,
                                                const _Float16* __restrict__ wihL,
                                                const _Float16* __restrict__ whhH,
                                                const _Float16* __restrict__ whhL,
                                                const float* __restrict__ bih,
                                                const float* __restrict__ bhh,
                                                _Float16* __restrict__ oH,
                                                _Float16* __restrict__ oL) {
    const int tid = threadIdx.x;
    const int wid = tid >> 6, lane = tid & 63;
    const int lr = lane & 15, lk = lane >> 4;
    const int wr = wid >> 1, wc = wid & 1;
    const int m0 = blockIdx.y << 6;
    const int j0 = blockIdx.x << 6;
    int arow[2];
    arow[0] = min(m0 + wr * 32 + lr, N_NODESC - 1);
    arow[1] = min(m0 + wr * 32 + 16 + lr, N_NODESC - 1);
    const int jb = j0 + wc * 32 + lr;
    const int kb = lk * 8;
    f4v accI[3][2][2], accH[3][2][2];
    const f4v z4 = {0.f, 0.f, 0.f, 0.f};
#pragma unroll
    for (int g = 0; g < 3; ++g)
#pragma unroll
        for (int a = 0; a < 2; ++a)
#pragma unroll
            for (int b = 0; b < 2; ++b) { accI[g][a][b] = z4; accH[g][a][b] = z4; }

    for (int k0 = 0; k0 < HD; k0 += 32) {
        h8v Aah[2], Aal[2], Ahh[2], Ahl[2];
#pragma unroll
        for (int sm = 0; sm < 2; ++sm) {
            const size_t off = (size_t)arow[sm] * HD + k0 + kb;
            Aah[sm] = *(const h8v*)(aH + off);
            Aal[sm] = *(const h8v*)(aL + off);
            Ahh[sm] = *(const h8v*)(hH + off);
            Ahl[sm] = *(const h8v*)(hL + off);
        }
#pragma unroll
        for (int g = 0; g < 3; ++g) {
            h8v BiH[2], BiL[2], BhH[2], BhL[2];
#pragma unroll
            for (int sn = 0; sn < 2; ++sn) {
                const size_t woff = (size_t)(g * HD + jb + sn * 16) * HD + k0 + kb;
                BiH[sn] = *(const h8v*)(wihH + woff);
                BiL[sn] = *(const h8v*)(wihL + woff);
                BhH[sn] = *(const h8v*)(whhH + woff);
                BhL[sn] = *(const h8v*)(whhL + woff);
            }
#pragma unroll
            for (int sm = 0; sm < 2; ++sm)
#pragma unroll
                for (int sn = 0; sn < 2; ++sn) {
                    f4v ai = accI[g][sm][sn];
                    ai = __builtin_amdgcn_mfma_f32_16x16x32_f16(Aah[sm], BiH[sn], ai, 0, 0, 0);
                    ai = __builtin_amdgcn_mfma_f32_16x16x32_f16(Aah[sm], BiL[sn], ai, 0, 0, 0);
                    ai = __builtin_amdgcn_mfma_f32_16x16x32_f16(Aal[sm], BiH[sn], ai, 0, 0, 0);
                    accI[g][sm][sn] = ai;
                    f4v ah = accH[g][sm][sn];
                    ah = __builtin_amdgcn_mfma_f32_16x16x32_f16(Ahh[sm], BhH[sn], ah, 0, 0, 0);
                    ah = __builtin_amdgcn_mfma_f32_16x16x32_f16(Ahh[sm], BhL[sn], ah, 0, 0, 0);
                    ah = __builtin_amdgcn_mfma_f32_16x16x32_f16(Ahl[sm], BhH[sn], ah, 0, 0, 0);
                    accH[g][sm][sn] = ah;
                }
        }
    }
    // epilogue: gates + GRU update; writes h' as hi/lo halves
#pragma unroll
    for (int sm = 0; sm < 2; ++sm)
#pragma unroll
        for (int sn = 0; sn < 2; ++sn) {
            const int col = j0 + wc * 32 + sn * 16 + lr;
            const float bri = bih[col], bzi = bih[HD + col], bni = bih[2 * HD + col];
            const float brh = bhh[col], bzh = bhh[HD + col], bnh = bhh[2 * HD + col];
#pragma unroll
            for (int j = 0; j < 4; ++j) {
                const int row = m0 + wr * 32 + sm * 16 + lk * 4 + j;
                if (row < N_NODESC) {
                    const size_t off = (size_t)row * HD + col;
                    const float hold = (float)hH[off] + (float)hL[off];
                    const float r = sigmoidf_((accI[0][sm][sn][j] + bri) + (accH[0][sm][sn][j] + brh));
                    const float z = sigmoidf_((accI[1][sm][sn][j] + bzi) + (accH[1][sm][sn][j] + bzh));
                    const float n = tanhf((accI[2][sm][sn][j] + bni) + r * (accH[2][sm][sn][j] + bnh));
                    const float res = (1.f - z) * n + z * hold;
                    const _Float16 hh = (_Float16)res;
                    oH[off] = hh;
                    oL[off] = (_Float16)(res - (float)hh);
                }
            }
        }
}

// ================= edge scatter (reads hi/lo m, int32 atomics) =================
__global__ __launch_bounds__(256) void scatter_add_h(const _Float16* __restrict__ mH,
                                                     const _Float16* __restrict__ mL,
                                                     const int* __restrict__ src,
                                                     const int* __restrict__ dst,
                                                     int* __restrict__ aggi) {
    const int gid = blockIdx.x * 256 + threadIdx.x;  // E*96 exact
    const int e = gid / 96;
    const int c = gid % 96;
    if (e >= N_EDGESC) return;
    const int s = src[e], d = dst[e];
    const size_t so = (size_t)s * HD + (c << 2);
    const h4v vh = *(const h4v*)(mH + so);
    const h4v vl = *(const h4v*)(mL + so);
    int* o = aggi + (size_t)d * HD + (c << 2);
    atomicAdd(o + 0, __float2int_rn(((float)vh[0] + (float)vl[0]) * FPSCALE));
    atomicAdd(o + 1, __float2int_rn(((float)vh[1] + (float)vl[1]) * FPSCALE));
    atomicAdd(o + 2, __float2int_rn(((float)vh[2] + (float)vl[2]) * FPSCALE));
    atomicAdd(o + 3, __float2int_rn(((float)vh[3] + (float)vl[3]) * FPSCALE));
}

// aggi (int) -> a_hi/a_lo halves
__global__ __launch_bounds__(256) void split_agg(const int* __restrict__ aggi,
                                                 _Float16* __restrict__ hi,
                                                 _Float16* __restrict__ lo) {
    const size_t i = (size_t)blockIdx.x * 256 + threadIdx.x;  // NH/4 exact
    const int4 q = ((const int4*)aggi)[i];
    h4v a, b;
    float v;
    v = q.x * FPINV; a[0] = (_Float16)v; b[0] = (_Float16)(v - (float)a[0]);
    v = q.y * FPINV; a[1] = (_Float16)v; b[1] = (_Float16)(v - (float)a[1]);
    v = q.z * FPINV; a[2] = (_Float16)v; b[2] = (_Float16)(v - (float)a[2]);
    v = q.w * FPINV; a[3] = (_Float16)v; b[3] = (_Float16)(v - (float)a[3]);
    *(h4v*)(hi + i * 4) = a;
    *(h4v*)(lo + i * 4) = b;
}

// ================= BN stats (deterministic two-stage) =================
__global__ __launch_bounds__(384) void col_stats_partial(const float* __restrict__ X, int M,
                                                         float* __restrict__ pS,
                                                         float* __restrict__ pQ) {
    const int f = threadIdx.x;
    const int b = blockIdx.x;
    const int r0 = b * STATS_ROWS;
    const int r1 = min(r0 + STATS_ROWS, M);
    float s = 0.f, q = 0.f;
    for (int r = r0; r < r1; ++r) {
        const float v = X[(size_t)r * HD + f];
        s += v;
        q += v * v;
    }
    pS[b * HD + f] = s;
    pQ[b * HD + f] = q;
}

__global__ __launch_bounds__(384) void col_stats_h(const _Float16* __restrict__ hH,
                                                   const _Float16* __restrict__ hL, int M,
                                                   float* __restrict__ pS,
                                                   float* __restrict__ pQ) {
    const int f = threadIdx.x;
    const int b = blockIdx.x;
    const int r0 = b * STATS_ROWS;
    const int r1 = min(r0 + STATS_ROWS, M);
    float s = 0.f, q = 0.f;
    for (int r = r0; r < r1; ++r) {
        const size_t off = (size_t)r * HD + f;
        const float v = (float)hH[off] + (float)hL[off];
        s += v;
        q += v * v;
    }
    pS[b * HD + f] = s;
    pQ[b * HD + f] = q;
}

__global__ void bn_stats_final(const float* __restrict__ pS, const float* __restrict__ pQ,
                               const float* __restrict__ g, const float* __restrict__ b,
                               float* __restrict__ scale, float* __restrict__ shift, float invM) {
    const int f = threadIdx.x;
    float s = 0.f, q = 0.f;
    for (int blk = 0; blk < STATS_BLOCKS; ++blk) {
        s += pS[blk * HD + f];
        q += pQ[blk * HD + f];
    }
    const float mean = s * invM;
    const float var = q * invM - mean * mean;
    const float sc = g[f] * rsqrtf(var + BN_EPS);
    scale[f] = sc;
    shift[f] = b[f] - mean * sc;
}

// relu(X*scale+shift) -> hi/lo halves
__global__ __launch_bounds__(256) void bn_relu_split(const float* __restrict__ X,
                                                     const float* __restrict__ scale,
                                                     const float* __restrict__ shift,
                                                     _Float16* __restrict__ hH,
                                                     _Float16* __restrict__ hL) {
    const size_t i4 = (size_t)blockIdx.x * 256 + threadIdx.x;  // NH/4 exact
    const int f = (int)((i4 * 4) % HD);
    const float4 v = ((const float4*)X)[i4];
    float r0 = fmaxf(fmaf(v.x, scale[f + 0], shift[f + 0]), 0.f);
    float r1 = fmaxf(fmaf(v.y, scale[f + 1], shift[f + 1]), 0.f);
    float r2 = fmaxf(fmaf(v.z, scale[f + 2], shift[f + 2]), 0.f);
    float r3 = fmaxf(fmaf(v.w, scale[f + 3], shift[f + 3]), 0.f);
    h4v a, b;
    a[0] = (_Float16)r0; b[0] = (_Float16)(r0 - (float)a[0]);
    a[1] = (_Float16)r1; b[1] = (_Float16)(r1 - (float)a[1]);
    a[2] = (_Float16)r2; b[2] = (_Float16)(r2 - (float)a[2]);
    a[3] = (_Float16)r3; b[3] = (_Float16)(r3 - (float)a[3]);
    *(h4v*)(hH + i4 * 4) = a;
    *(h4v*)(hL + i4 * 4) = b;
}

// fp32 bn+relu (in place ok) — for skip recompute
__global__ __launch_bounds__(256) void bn_relu_apply(const float* X,
                                                     const float* __restrict__ scale,
                                                     const float* __restrict__ shift,
                                                     float* h) {
    const size_t i4 = (size_t)blockIdx.x * 256 + threadIdx.x;
    const int f = (int)((i4 * 4) % HD);
    const float4 v = ((const float4*)X)[i4];
    float4 r;
    r.x = fmaxf(fmaf(v.x, scale[f + 0], shift[f + 0]), 0.f);
    r.y = fmaxf(fmaf(v.y, scale[f + 1], shift[f + 1]), 0.f);
    r.z = fmaxf(fmaf(v.z, scale[f + 2], shift[f + 2]), 0.f);
    r.w = fmaxf(fmaf(v.w, scale[f + 3], shift[f + 3]), 0.f);
    ((float4*)h)[i4] = r;
}

// hfinal = relu((hH+hL)*scale + shift + skip)  (fp32 out)
__global__ __launch_bounds__(256) void bn_skip_relu_h(const _Float16* __restrict__ hH,
                                                      const _Float16* __restrict__ hL,
                                                      const float* __restrict__ scale,
                                                      const float* __restrict__ shift,
                                                      const float* __restrict__ skip,
                                                      float* __restrict__ out) {
    const size_t i4 = (size_t)blockIdx.x * 256 + threadIdx.x;
    const int f = (int)((i4 * 4) % HD);
    const h4v a = *(const h4v*)(hH + i4 * 4);
    const h4v b = *(const h4v*)(hL + i4 * 4);
    const float4 s = ((const float4*)skip)[i4];
    float4 r;
    r.x = fmaxf(fmaf((float)a[0] + (float)b[0], scale[f + 0], shift[f + 0]) + s.x, 0.f);
    r.y = fmaxf(fmaf((float)a[1] + (float)b[1], scale[f + 1], shift[f + 1]) + s.y, 0.f);
    r.z = fmaxf(fmaf((float)a[2] + (float)b[2], scale[f + 2], shift[f + 2]) + s.z, 0.f);
    r.w = fmaxf(fmaf((float)a[3] + (float)b[3], scale[f + 3], shift[f + 3]) + s.w, 0.f);
    ((float4*)out)[i4] = r;
}

// ================= attention pooling + head (unchanged) =================
__global__ __launch_bounds__(64) void att_logits(const float* __restrict__ h2,
                                                 const float* __restrict__ att_w,
                                                 const float* __restrict__ att_b,
                                                 float* __restrict__ logits) {
    const int n = blockIdx.x;
    const int l = threadIdx.x;
    float acc = 0.f;
#pragma unroll
    for (int k = 0; k < HD; k += 64) acc += h2[(size_t)n * HD + k + l] * att_w[k + l];
#pragma unroll
    for (int o = 32; o > 0; o >>= 1) acc += __shfl_down(acc, o);
    if (l == 0) logits[n] = acc + att_b[0];
}

__global__ void count_graphs(const int* __restrict__ batch, int* __restrict__ counts) {
    const int n = blockIdx.x * 256 + threadIdx.x;
    if (n < N_NODESC) atomicAdd(&counts[batch[n]], 1);
}

__global__ void scan_offsets(const int* __restrict__ counts, int* __restrict__ offs) {
    __shared__ int tmp[N_GRAPHSC];
    const int t = threadIdx.x;
    tmp[t] = counts[t];
    __syncthreads();
    for (int o = 1; o < N_GRAPHSC; o <<= 1) {
        int v = (t >= o) ? tmp[t - o] : 0;
        __syncthreads();
        tmp[t] += v;
        __syncthreads();
    }
    offs[t] = tmp[t] - counts[t];
}

__global__ __launch_bounds__(384) void pool_graphs(const float* __restrict__ h2,
                                                   const float* __restrict__ logits,
                                                   const int* __restrict__ offs,
                                                   const int* __restrict__ counts,
                                                   float* __restrict__ pooled) {
    const int g = blockIdx.x;
    const int t = threadIdx.x;
    const int s = offs[g], c = counts[g], e = s + c;
    __shared__ float red[384];
    float mx = -1e30f;
    for (int n = s + t; n < e; n += 384) mx = fmaxf(mx, logits[n]);
    red[t] = mx;
    __syncthreads();
    if (t < 128) red[t] = fmaxf(red[t], fmaxf(red[t + 128], red[t + 256]));
    __syncthreads();
    for (int w = 64; w > 0; w >>= 1) {
        if (t < w) red[t] = fmaxf(red[t], red[t + w]);
        __syncthreads();
    }
    mx = red[0];
    __syncthreads();
    float sm = 0.f;
    for (int n = s + t; n < e; n += 384) sm += expf(logits[n] - mx);
    red[t] = sm;
    __syncthreads();
    if (t < 128) red[t] += red[t + 128] + red[t + 256];
    __syncthreads();
    for (int w = 64; w > 0; w >>= 1) {
        if (t < w) red[t] += red[t + w];
        __syncthreads();
    }
    const float denom = red[0];
    const float inv = (c > 0) ? 1.0f / denom : 0.0f;
    float acc = 0.f;
    for (int n = s; n < e; ++n) acc += expf(logits[n] - mx) * h2[(size_t)n * HD + t];
    pooled[(size_t)g * HD + t] = acc * inv;
}

__global__ void fc_small(const float* __restrict__ X, const float* __restrict__ W,
                         const float* __restrict__ bias, float* __restrict__ Y,
                         int K, int N) {
    const int m = blockIdx.x;
    const int n = threadIdx.x;
    if (n >= N) return;
    float acc = bias[n];
    for (int k = 0; k < K; ++k) acc += X[m * K + k] * W[k * N + n];
    Y[m * N + n] = acc;
}

__global__ void bn_small_relu(float* X, int M, int N,
                              const float* __restrict__ g, const float* __restrict__ b) {
    const int f = threadIdx.x;
    if (f >= N) return;
    float s = 0.f, q = 0.f;
    for (int r = 0; r < M; ++r) {
        const float v = X[r * N + f];
        s += v;
        q += v * v;
    }
    const float mean = s / M;
    const float var = q / M - mean * mean;
    const float sc = g[f] * rsqrtf(var + BN_EPS);
    const float sh = b[f] - mean * sc;
    for (int r = 0; r < M; ++r) X[r * N + f] = fmaxf(X[r * N + f] * sc + sh, 0.f);
}

extern "C" void kernel_launch(void* const* d_in, const int* in_sizes, int n_in,
                              void* d_out, int out_size, void* d_ws, size_t ws_size,
                              hipStream_t stream) {
    const float* x       = (const float*)d_in[0];
    const int*   eidx    = (const int*)d_in[1];
    const int*   batch   = (const int*)d_in[2];
    const float* w_in    = (const float*)d_in[3];
    const float* b_in    = (const float*)d_in[4];
    const float* bn1_g   = (const float*)d_in[5];
    const float* bn1_b   = (const float*)d_in[6];
    const float* ggc_w   = (const float*)d_in[7];
    const float* gru_wih = (const float*)d_in[8];
    const float* gru_whh = (const float*)d_in[9];
    const float* gru_bih = (const float*)d_in[10];
    const float* gru_bhh = (const float*)d_in[11];
    const float* bn2_g   = (const float*)d_in[12];
    const float* bn2_b   = (const float*)d_in[13];
    const float* att_w   = (const float*)d_in[14];
    const float* att_b   = (const float*)d_in[15];
    const float* fc1_w   = (const float*)d_in[16];
    const float* fc1_b   = (const float*)d_in[17];
    const float* bn3_g   = (const float*)d_in[18];
    const float* bn3_b   = (const float*)d_in[19];
    const float* fc2_w   = (const float*)d_in[20];
    const float* fc2_b   = (const float*)d_in[21];
    const float* bn4_g   = (const float*)d_in[22];
    const float* bn4_b   = (const float*)d_in[23];
    const float* fc3_w   = (const float*)d_in[24];
    const float* fc3_b   = (const float*)d_in[25];

    const int* src = eidx;
    const int* dst = eidx + N_EDGESC;

    // ---- workspace carve (~237 MB; known-good budget <256 MiB) ----
    const size_t NH = (size_t)N_NODESC * HD;  // 19.2M elems
    char* p = (char*)d_ws;
    float* R0 = (float*)p; p += NH * sizeof(float);   // rotating region 0
    float* R1 = (float*)p; p += NH * sizeof(float);   // rotating region 1
    _Float16* mH = (_Float16*)p;                      // M region: m hi/lo -> agg hi/lo -> hfinal
    _Float16* mL = mH + NH; p += NH * sizeof(float);
    _Float16* wihH = (_Float16*)p; p += 3 * HD * HD * sizeof(_Float16);
    _Float16* wihL = (_Float16*)p; p += 3 * HD * HD * sizeof(_Float16);
    _Float16* whhH = (_Float16*)p; p += 3 * HD * HD * sizeof(_Float16);
    _Float16* whhL = (_Float16*)p; p += 3 * HD * HD * sizeof(_Float16);
    _Float16* ggcTH = (_Float16*)p; p += (size_t)STEPSC * HD * HD * sizeof(_Float16);
    _Float16* ggcTL = (_Float16*)p; p += (size_t)STEPSC * HD * HD * sizeof(_Float16);
    float* logits = (float*)p; p += N_NODESC * sizeof(float);
    float* pS = (float*)p; p += STATS_BLOCKS * HD * sizeof(float);
    float* pQ = (float*)p; p += STATS_BLOCKS * HD * sizeof(float);
    float* scale  = (float*)p; p += HD * sizeof(float);
    float* shift  = (float*)p; p += HD * sizeof(float);
    float* scale1 = (float*)p; p += HD * sizeof(float);
    float* shift1 = (float*)p; p += HD * sizeof(float);
    float* pooled = (float*)p; p += N_GRAPHSC * HD * sizeof(float);
    float* y1 = (float*)p; p += N_GRAPHSC * HD * sizeof(float);
    float* y2 = (float*)p; p += N_GRAPHSC * (HD / 2) * sizeof(float);
    int* counts = (int*)p; p += N_GRAPHSC * sizeof(int);
    int* offs = (int*)p;

    const dim3 mfma_grid(HD / 64, (N_NODESC + 63) / 64);  // (6, 782)
    const int ew_blocks = (int)(NH / 4 / 256);            // 18750 exact

    // 0) weight prep: fp16x2 splits (deterministic, recomputed each call)
    split_w<<<(3 * HD * HD / 4 + 255) / 256, 256, 0, stream>>>(gru_wih, wihH, wihL, 3 * HD * HD / 4);
    split_w<<<(3 * HD * HD / 4 + 255) / 256, 256, 0, stream>>>(gru_whh, whhH, whhL, 3 * HD * HD / 4);
    tsplit_ggc<<<(STEPSC * HD * HD + 255) / 256, 256, 0, stream>>>(ggc_w, ggcTH, ggcTL);

    // 1) input layer (fp32) + bn1 -> h halves in R1
    gemm64<<<dim3(HD / 64, (N_NODESC + 63) / 64), 256, 0, stream>>>(x, w_in, b_in, R0,
                                                                    N_NODESC, D_INC, HD);
    col_stats_partial<<<STATS_BLOCKS, 384, 0, stream>>>(R0, N_NODESC, pS, pQ);
    bn_stats_final<<<1, 384, 0, stream>>>(pS, pQ, bn1_g, bn1_b, scale1, shift1, 1.0f / N_NODESC);
    bn_relu_split<<<ew_blocks, 256, 0, stream>>>(R0, scale1, shift1, (_Float16*)R1,
                                                 (_Float16*)R1 + NH);

    // 2) GatedGraphConv loop: H region <-> other region rotation
    float* Hcur = R1;
    float* Oth = R0;
    for (int s7 = 0; s7 < STEPSC; ++s7) {
        const _Float16* hcH = (const _Float16*)Hcur;
        const _Float16* hcL = (const _Float16*)Hcur + NH;
        ggc_mfma<<<mfma_grid, 256, 0, stream>>>(hcH, hcL,
                                                ggcTH + (size_t)s7 * HD * HD,
                                                ggcTL + (size_t)s7 * HD * HD, mH, mL);
        hipMemsetAsync(Oth, 0, NH * sizeof(int), stream);
        scatter_add_h<<<(N_EDGESC * 96) / 256, 256, 0, stream>>>(mH, mL, src, dst, (int*)Oth);
        split_agg<<<ew_blocks, 256, 0, stream>>>((const int*)Oth, mH, mL);  // a_hi/a_lo overwrite m
        gru_mfma<<<mfma_grid, 256, 0, stream>>>(mH, mL, hcH, hcL, wihH, wihL, whhH, whhL,
                                                gru_bih, gru_bhh,
                                                (_Float16*)Oth, (_Float16*)Oth + NH);
        float* t = Hcur; Hcur = Oth; Oth = t;
    }

    // 3) bn2 on h (halves) + skip recompute (fp32) + fused bn2+skip+relu -> hfinal (M region)
    const _Float16* hfH = (const _Float16*)Hcur;
    const _Float16* hfL = (const _Float16*)Hcur + NH;
    col_stats_h<<<STATS_BLOCKS, 384, 0, stream>>>(hfH, hfL, N_NODESC, pS, pQ);
    bn_stats_final<<<1, 384, 0, stream>>>(pS, pQ, bn2_g, bn2_b, scale, shift, 1.0f / N_NODESC);
    gemm64<<<dim3(HD / 64, (N_NODESC + 63) / 64), 256, 0, stream>>>(x, w_in, b_in, Oth,
                                                                    N_NODESC, D_INC, HD);
    bn_relu_apply<<<ew_blocks, 256, 0, stream>>>(Oth, scale1, shift1, Oth);
    float* hfinal = (float*)mH;
    bn_skip_relu_h<<<ew_blocks, 256, 0, stream>>>(hfH, hfL, scale, shift, Oth, hfinal);

    // 4) attention pooling
    att_logits<<<N_NODESC, 64, 0, stream>>>(hfinal, att_w, att_b, logits);
    hipMemsetAsync(counts, 0, N_GRAPHSC * sizeof(int), stream);
    count_graphs<<<(N_NODESC + 255) / 256, 256, 0, stream>>>(batch, counts);
    scan_offsets<<<1, N_GRAPHSC, 0, stream>>>(counts, offs);
    pool_graphs<<<N_GRAPHSC, 384, 0, stream>>>(hfinal, logits, offs, counts, pooled);

    // 5) MLP head
    fc_small<<<N_GRAPHSC, 384, 0, stream>>>(pooled, fc1_w, fc1_b, y1, HD, HD);
    bn_small_relu<<<1, 384, 0, stream>>>(y1, N_GRAPHSC, HD, bn3_g, bn3_b);
    fc_small<<<N_GRAPHSC, 192, 0, stream>>>(y1, fc2_w, fc2_b, y2, HD, HD / 2);
    bn_small_relu<<<1, 192, 0, stream>>>(y2, N_GRAPHSC, HD / 2, bn4_g, bn4_b);
    fc_small<<<N_GRAPHSC, 64, 0, stream>>>(y2, fc3_w, fc3_b, (float*)d_out, HD / 2, 2);
}